// Round 6
// baseline (424.523 us; speedup 1.0000x reference)
//
#include <hip/hip_runtime.h>
#include <hip/hip_bf16.h>
#include <stdint.h>

// Problem constants
#define L_DIM 4096
#define B_DIM 32
#define H_DIM 512
#define M_DIM (L_DIM * B_DIM)  // 131072 rows of the fused GEMM
#define K_DIM H_DIM            // 512 reduction dim

typedef _Float16 half8 __attribute__((ext_vector_type(8)));
typedef __fp16 fp16x2 __attribute__((ext_vector_type(2)));  // cvt_pkrtz return type
typedef float floatx4 __attribute__((ext_vector_type(4)));

// tanh(x) = 1 - 2/(1 + e^{2x}), via hw exp2 + rcp (~1e-7 abs err, saturates correctly)
__device__ __forceinline__ float tanh_fast(float x) {
  float e = __builtin_amdgcn_exp2f(x * 2.88539008177793f);  // 2*log2(e)
  return 1.0f - 2.0f * __builtin_amdgcn_rcpf(e + 1.0f);
}

__device__ __forceinline__ uint2 pack4(const float4& f) {
  const fp16x2 p0 = __builtin_amdgcn_cvt_pkrtz(f.x, f.y);
  const fp16x2 p1 = __builtin_amdgcn_cvt_pkrtz(f.z, f.w);
  uint2 u;
  u.x = __builtin_bit_cast(unsigned, p0);
  u.y = __builtin_bit_cast(unsigned, p1);
  return u;
}

// ---------------------------------------------------------------------------
// Merged prep (512 threads): blocks [0,64) build W2 (Wk fp16, fragment-packed);
// blocks [64,96) compute q_proj with 4-way K-split + LDS reduce.
// W2 chunk c = ((kt*32 + nc)*4 + q)*16 + l15 holds Wk[k=kt*32+q*8+j][n=nc*16+l15].
__global__ __launch_bounds__(512) void prep_kernel(const float* __restrict__ query,
                                                   const float* __restrict__ W,
                                                   float* __restrict__ qp,
                                                   _Float16* __restrict__ W2) {
  __shared__ float4 qred[512];
  if (blockIdx.x < 64) {
    // ---- wconv: Wk (=W[512:]) -> packed fp16 chunks
    const int t = blockIdx.x * 512 + threadIdx.x;  // [0, 32768) chunk index
    const int l15 = t & 15;
    const int q = (t >> 4) & 3;
    const int nc = (t >> 6) & 31;
    const int kt = t >> 11;
    const int n = nc * 16 + l15;
    const int kbase = H_DIM + kt * 32 + q * 8;  // Wk rows live at W[512 + k]
    half8 h;
#pragma unroll
    for (int j = 0; j < 8; ++j)
      h[j] = (_Float16)W[(size_t)(kbase + j) * H_DIM + n];
    *(half8*)(W2 + (size_t)t * 8) = h;
  } else {
    // ---- qproj: q_proj[b][h] = sum_i query[b][i] * W[i][h], 4-way K-split
    const int b = blockIdx.x - 64;
    const int tid = threadIdx.x;
    const int hx = tid & 127;       // h-column group
    const int ky = tid >> 7;        // K-chunk [0,4)
    const int h = hx * 4;
    const float* qrow = query + b * H_DIM + ky * 128;
    const float* wrow = W + (size_t)(ky * 128) * H_DIM + h;
    float4 acc = make_float4(0.f, 0.f, 0.f, 0.f);
#pragma unroll 8
    for (int i = 0; i < 128; ++i) {
      const float qv = qrow[i];
      const float4 w4 = *(const float4*)(wrow + (size_t)i * H_DIM);
      acc.x += qv * w4.x; acc.y += qv * w4.y;
      acc.z += qv * w4.z; acc.w += qv * w4.w;
    }
    qred[tid] = acc;
    __syncthreads();
    if (ky == 0) {
      const float4 a1 = qred[tid + 128], a2 = qred[tid + 256], a3 = qred[tid + 384];
      acc.x += a1.x + a2.x + a3.x;
      acc.y += a1.y + a2.y + a3.y;
      acc.z += a1.z + a2.z + a3.z;
      acc.w += a1.w + a2.w + a3.w;
      *(float4*)(qp + (size_t)b * H_DIM + h) = acc;
    }
  }
}

// ---------------------------------------------------------------------------
// Fused GEMM + tanh + v-dot, v4: 64 rows x 512 cols per block, 8 col-stripe
// waves, 2 blocks/CU.
// vs v3 (R5): B prefetch RESTORED -- B(kt+1) issued at top of epoch kt into
// the bn ping-pong and consumed directly by MFMA next epoch (full-epoch L2
// latency cover; v3 exposed ~300cyc B latency to all barrier-synced waves
// every epoch). A-fragment reads chunked 2+2 so the av live set stays at 2
// (VGPR budget: acc 64 + bn 32 + rb 8 + av 8 + addr ~12 <= 128 keeps
// 2 blocks/CU), and the first 8 MFMAs overlap the second ds_read pair.
// A-path: reg-staged fp16 LDS double-buffer (pack once at write; single
// ds_read_b128 per fragment; bank-uniform 64B row stride).
// Sync: raw s_barrier + lgkmcnt(0) only -- no vmcnt drain, so A/B global
// loads stay in flight across barriers (compiler exact-counts their deps).
__global__ __launch_bounds__(512, 4) void fused_gemm_kernel(
    const float* __restrict__ key, const _Float16* __restrict__ W2,
    const float* __restrict__ qp, const float* __restrict__ v,
    float* __restrict__ scores) {
  __shared__ __align__(16) _Float16 As[2][64 * 32];  // 2 x 4 KB fp16 k-slices
  __shared__ float swave[8 * 64];

  const int tid = threadIdx.x;
  const int lane = tid & 63;
  const int wn = tid >> 6;        // wave id = column stripe [0,8)
  const int l15 = lane & 15;
  const int quad = lane >> 4;
  const int m0 = blockIdx.x * 64;

  // A staging: thread t covers row t>>3 (0..63), 16B k-chunk t&7
  const int srow = tid >> 3;
  const int schunk = tid & 7;
  const float* ag = key + (size_t)(m0 + srow) * K_DIM + schunk * 4;
  const int adst = srow * 32 + schunk * 4;  // halves

  // B: chunk index for (kt, fn) = (kt*32 + wn*4 + fn)*64 + lane; 16B chunks
  const half8* bptr = (const half8*)W2 + (size_t)(wn * 4) * 64 + lane;

  floatx4 acc[4][4];
#pragma unroll
  for (int fm = 0; fm < 4; ++fm)
#pragma unroll
    for (int fn = 0; fn < 4; ++fn) acc[fm][fn] = (floatx4)0.0f;

  half8 bn[2][4];

  // prologue: A(0) -> LDS buf0 directly; prefetch A(1), A(2) regs; B(0) regs
  float4 ra0 = *(const float4*)(ag);
  float4 rb[2];
  rb[1] = *(const float4*)(ag + 32);   // A(1), written at epoch 0
  rb[0] = *(const float4*)(ag + 64);   // A(2), written at epoch 1
#pragma unroll
  for (int fn = 0; fn < 4; ++fn) bn[0][fn] = bptr[fn * 64];
  bptr += 32 * 64;
  *(uint2*)(As[0] + adst) = pack4(ra0);
  asm volatile("s_waitcnt lgkmcnt(0)" ::: "memory");
  __builtin_amdgcn_s_barrier();
  __builtin_amdgcn_sched_barrier(0);

#pragma unroll
  for (int kt = 0; kt < 16; ++kt) {
    // issue B(kt+1): consumed next epoch (full-epoch latency cover)
    if (kt < 15) {
#pragma unroll
      for (int fn = 0; fn < 4; ++fn) bn[(kt + 1) & 1][fn] = bptr[fn * 64];
      bptr += 32 * 64;
    }

    const _Float16* buf = As[kt & 1];
    // A fragments fm=0,1 (single b128 each)
    half8 av0 = *(const half8*)(buf + (0 * 16 + l15) * 32 + quad * 8);
    half8 av1 = *(const half8*)(buf + (1 * 16 + l15) * 32 + quad * 8);

    if (kt < 15) {
      // stage A(kt+1) into other buffer (reg loaded 2 epochs ago)
      *(uint2*)(As[(kt + 1) & 1] + adst) = pack4(rb[(kt + 1) & 1]);
      if (kt < 13) rb[(kt + 1) & 1] = *(const float4*)(ag + (kt + 3) * 32);
    }

#pragma unroll
    for (int fn = 0; fn < 4; ++fn)
      acc[0][fn] = __builtin_amdgcn_mfma_f32_16x16x32_f16(av0, bn[kt & 1][fn],
                                                          acc[0][fn], 0, 0, 0);
#pragma unroll
    for (int fn = 0; fn < 4; ++fn)
      acc[1][fn] = __builtin_amdgcn_mfma_f32_16x16x32_f16(av1, bn[kt & 1][fn],
                                                          acc[1][fn], 0, 0, 0);

    // A fragments fm=2,3 overlap the MFMAs above
    half8 av2 = *(const half8*)(buf + (2 * 16 + l15) * 32 + quad * 8);
    half8 av3 = *(const half8*)(buf + (3 * 16 + l15) * 32 + quad * 8);

#pragma unroll
    for (int fn = 0; fn < 4; ++fn)
      acc[2][fn] = __builtin_amdgcn_mfma_f32_16x16x32_f16(av2, bn[kt & 1][fn],
                                                          acc[2][fn], 0, 0, 0);
#pragma unroll
    for (int fn = 0; fn < 4; ++fn)
      acc[3][fn] = __builtin_amdgcn_mfma_f32_16x16x32_f16(av3, bn[kt & 1][fn],
                                                          acc[3][fn], 0, 0, 0);

    __builtin_amdgcn_sched_barrier(0);
    asm volatile("s_waitcnt lgkmcnt(0)" ::: "memory");  // own ds ops landed
    __builtin_amdgcn_s_barrier();                        // all waves' writes landed
    __builtin_amdgcn_sched_barrier(0);
  }

  // Epilogue: score[m] = sum_n v[n] * tanh(qp[m&31][n] + kproj[m][n])
  // C/D layout: col = lane&15, row = quad*4 + reg (verified: passes)
  float vv[4];
#pragma unroll
  for (int fn = 0; fn < 4; ++fn) vv[fn] = v[wn * 64 + fn * 16 + l15];

#pragma unroll
  for (int fm = 0; fm < 4; ++fm) {
#pragma unroll
    for (int r = 0; r < 4; ++r) {
      const int mrow = fm * 16 + quad * 4 + r;
      const float* qrow = qp + (size_t)(mrow & 31) * H_DIM;
      float rs = 0.f;
#pragma unroll
      for (int fn = 0; fn < 4; ++fn) {
        const int n = wn * 64 + fn * 16 + l15;
        const float x = qrow[n] + acc[fm][fn][r];
        rs += vv[fn] * tanh_fast(x);
      }
      rs += __shfl_xor(rs, 1);
      rs += __shfl_xor(rs, 2);
      rs += __shfl_xor(rs, 4);
      rs += __shfl_xor(rs, 8);
      if (l15 == 0) swave[wn * 64 + mrow] = rs;
    }
  }
  __syncthreads();
  if (tid < 64) {
    float s = 0.f;
#pragma unroll
    for (int j = 0; j < 8; ++j) s += swave[j * 64 + tid];
    const int m = m0 + tid;  // m = l*32 + b
    scores[(size_t)(m & 31) * L_DIM + (m >> 5)] = s;  // transposed: [b][l]
  }
}

// ---------------------------------------------------------------------------
// softmax over l per b; scores already [b][l]; out[b][l] — fully coalesced.
// Wave shfl reductions: 2 barriers instead of 16.
__global__ __launch_bounds__(256) void softmax_kernel(const float* __restrict__ scores,
                                                      float* __restrict__ out) {
  const int b = blockIdx.x;
  const int t = threadIdx.x;
  const int lane = t & 63;
  const int w = t >> 6;
  __shared__ float redm[4], reds[4];
  const float* srow = scores + (size_t)b * L_DIM;
  float s[16];
#pragma unroll
  for (int i = 0; i < 16; ++i) s[i] = srow[t + i * 256];
  float mx = s[0];
#pragma unroll
  for (int i = 1; i < 16; ++i) mx = fmaxf(mx, s[i]);
#pragma unroll
  for (int off = 1; off < 64; off <<= 1) mx = fmaxf(mx, __shfl_xor(mx, off));
  if (lane == 0) redm[w] = mx;
  __syncthreads();
  mx = fmaxf(fmaxf(redm[0], redm[1]), fmaxf(redm[2], redm[3]));
  float sum = 0.f;
#pragma unroll
  for (int i = 0; i < 16; ++i) {
    s[i] = __builtin_amdgcn_exp2f((s[i] - mx) * 1.44269504f);
    sum += s[i];
  }
#pragma unroll
  for (int off = 1; off < 64; off <<= 1) sum += __shfl_xor(sum, off);
  if (lane == 0) reds[w] = sum;
  __syncthreads();
  const float inv = 1.0f / (reds[0] + reds[1] + reds[2] + reds[3]);
#pragma unroll
  for (int i = 0; i < 16; ++i) out[(size_t)b * L_DIM + t + i * 256] = s[i] * inv;
}

// ---------------------------------------------------------------------------
extern "C" void kernel_launch(void* const* d_in, const int* in_sizes, int n_in,
                              void* d_out, int out_size, void* d_ws, size_t ws_size,
                              hipStream_t stream) {
  const float* query = (const float*)d_in[0];
  const float* key   = (const float*)d_in[1];
  const float* W     = (const float*)d_in[2];
  const float* v     = (const float*)d_in[3];
  float* out = (float*)d_out;

  char* ws = (char*)d_ws;
  float* qp       = (float*)ws;                        // 32*512*4   = 64 KB
  float* scores   = (float*)(ws + 65536);              // 131072*4   = 512 KB
  _Float16* W2    = (_Float16*)(ws + 65536 + 524288);  // 512*512*2  = 512 KB

  prep_kernel<<<96, 512, 0, stream>>>(query, W, qp, W2);
  fused_gemm_kernel<<<M_DIM / 64, 512, 0, stream>>>(key, W2, qp, v, scores);
  softmax_kernel<<<B_DIM, 256, 0, stream>>>(scores, out);
}